// Round 11
// baseline (383.764 us; speedup 1.0000x reference)
//
#include <hip/hip_runtime.h>
#include <hip/hip_bf16.h>

#define BB 8
#define SQ 2048
#define SK 2048
#define DD 128
// 1/sqrt(128) * log2(e): K pre-scaled so QK acc feeds exp2 directly
#define KSCALE 0.12751649736401815f

using s16x8 = __attribute__((ext_vector_type(8))) short;
using f32x4 = __attribute__((ext_vector_type(4))) float;

__device__ __forceinline__ unsigned short f2bf(float f) {
  union { float f; unsigned u; } v; v.f = f;
  unsigned r = v.u + 0x7FFFu + ((v.u >> 16) & 1u);
  return (unsigned short)(r >> 16);
}
__device__ __forceinline__ float bf2f(unsigned short h) {
  union { unsigned u; float f; } v; v.u = ((unsigned)h) << 16; return v.f;
}
__device__ __forceinline__ void bar_lds() {
  asm volatile("s_waitcnt lgkmcnt(0)" ::: "memory");
  __builtin_amdgcn_s_barrier();
}

// Merged prep: [0,1024) K->bf16*KSCALE; [1024,1280) V->bf16 V^T; [1280,5376) maskpack
__global__ __launch_bounds__(256) void prep_all(
    const float* __restrict__ k, const float* __restrict__ v,
    const int* __restrict__ m, unsigned short* __restrict__ kb,
    unsigned short* __restrict__ vt, unsigned long long* __restrict__ mb) {
  const int bid = blockIdx.x;
  const int tid = threadIdx.x;
  if (bid < 1024) {            // ---- K scale+convert ----
    const size_t i = ((size_t)bid * 256 + tid) * 8;
    const float4 a = *(const float4*)(k + i);
    const float4 c = *(const float4*)(k + i + 4);
    ushort4 o0, o1;
    o0.x = f2bf(a.x * KSCALE); o0.y = f2bf(a.y * KSCALE);
    o0.z = f2bf(a.z * KSCALE); o0.w = f2bf(a.w * KSCALE);
    o1.x = f2bf(c.x * KSCALE); o1.y = f2bf(c.y * KSCALE);
    o1.z = f2bf(c.z * KSCALE); o1.w = f2bf(c.w * KSCALE);
    *(ushort4*)(kb + i) = o0;
    *(ushort4*)(kb + i + 4) = o1;
  } else if (bid < 1280) {     // ---- V transpose ----
    constexpr int TS = 132;
    __shared__ __align__(16) unsigned short tile[64 * TS];
    const int vb = bid - 1024;
    const int b  = vb >> 5;
    const int k0 = (vb & 31) << 6;
#pragma unroll
    for (int p = 0; p < 8; ++p) {
      const int row = p * 8 + (tid >> 5);
      const int c4  = (tid & 31) << 2;
      const float4 vv = *(const float4*)(v + ((size_t)(b * SK + k0 + row)) * DD + c4);
      ushort4 o; o.x = f2bf(vv.x); o.y = f2bf(vv.y); o.z = f2bf(vv.z); o.w = f2bf(vv.w);
      *(ushort4*)(&tile[row * TS + c4]) = o;
    }
    __syncthreads();
#pragma unroll
    for (int p = 0; p < 8; ++p) {
      const int u = p * 256 + tid;
      const int d  = u >> 4;
      const int kw = (u & 15) << 2;
      ushort4 o;
      o.x = tile[(kw + 0) * TS + d];
      o.y = tile[(kw + 1) * TS + d];
      o.z = tile[(kw + 2) * TS + d];
      o.w = tile[(kw + 3) * TS + d];
      *(ushort4*)(vt + ((size_t)(b * DD + d)) * SK + k0 + kw) = o;
    }
  } else {                     // ---- mask -> bits ----
    const int gw = ((bid - 1280) * 256 + tid) >> 6;  // global row
    const int lane = tid & 63;
    const int* rp = m + (size_t)gw * SK;
    unsigned long long* wp = mb + (size_t)gw * (SK / 64);
#pragma unroll 4
    for (int i = 0; i < 32; ++i) {
      const int mv = rp[i * 64 + lane];
      const unsigned long long bal = __ballot(mv != 0);
      if (lane == 0) wp[i] = bal;
    }
  }
}

#define BMSR 136  // mask-bit row stride (bytes): 128 data + 8 pad
#define LDP  136  // p_lds row stride (ushorts)

// Kernel A: partial softmax denominators. Block = (batch, 32-row tile, k-half).
// Grid 1024 -> 4 blocks/CU x 8 waves = 32 waves/CU; rt=2 keeps 2:1 MFMA:load.
__global__ __launch_bounds__(512, 8) void attn_lsum(
    const float* __restrict__ q, const unsigned long long* __restrict__ mb,
    const unsigned short* __restrict__ kb, float* __restrict__ lpart) {
  __shared__ unsigned char bm[32 * BMSR];
  __shared__ float redl[8][32];
  const int tid = threadIdx.x;
  const int bid = blockIdx.x;
  const int swz = ((bid & 7) << 7) + (bid >> 3);  // batch -> one XCD
  const int b  = swz >> 7;
  const int h  = swz & 1;
  const int q0 = ((swz >> 1) & 63) << 5;
  const int k0 = h << 10;
  const int lane = tid & 63, w = tid >> 6, lrow = lane & 15, lk = lane >> 4;
  const int rowb = lk << 2;
  const int colw = (w << 4) + lrow;

  {  // stage this half's mask bits: 32 rows x 16 u64
    const int row = tid >> 4, wd = tid & 15;
    *(unsigned long long*)&bm[row * BMSR + (wd << 3)] =
        mb[(size_t)(b * SQ + q0 + row) * 32 + h * 16 + wd];
  }

  s16x8 af0[4], af1[4];
#pragma unroll
  for (int ks = 0; ks < 4; ++ks) {
    const float* qp0 = q + ((size_t)(b * SQ + q0 + lrow)) * DD + ks * 32 + lk * 8;
    const float* qp1 = qp0 + 16 * DD;
    const float4 a0 = *(const float4*)qp0;
    const float4 a1 = *(const float4*)(qp0 + 4);
    const float4 c0 = *(const float4*)qp1;
    const float4 c1 = *(const float4*)(qp1 + 4);
    s16x8 x, y;
    x[0] = (short)f2bf(a0.x); x[1] = (short)f2bf(a0.y); x[2] = (short)f2bf(a0.z); x[3] = (short)f2bf(a0.w);
    x[4] = (short)f2bf(a1.x); x[5] = (short)f2bf(a1.y); x[6] = (short)f2bf(a1.z); x[7] = (short)f2bf(a1.w);
    y[0] = (short)f2bf(c0.x); y[1] = (short)f2bf(c0.y); y[2] = (short)f2bf(c0.z); y[3] = (short)f2bf(c0.w);
    y[4] = (short)f2bf(c1.x); y[5] = (short)f2bf(c1.y); y[6] = (short)f2bf(c1.z); y[7] = (short)f2bf(c1.w);
    af0[ks] = x; af1[ks] = y;
  }

  const unsigned short* kfp = kb + ((size_t)(b * SK + k0 + colw)) * DD + lk * 8;
  __syncthreads();  // bm ready

  float ls[8] = {0.f, 0.f, 0.f, 0.f, 0.f, 0.f, 0.f, 0.f};

  auto qk8 = [&](const s16x8* kf, f32x4& a0, f32x4& a1) {
    __builtin_amdgcn_s_setprio(1);
#pragma unroll
    for (int ks = 0; ks < 4; ++ks) {
      a0 = __builtin_amdgcn_mfma_f32_16x16x32_bf16(af0[ks], kf[ks], a0, 0, 0, 0);
      a1 = __builtin_amdgcn_mfma_f32_16x16x32_bf16(af1[ks], kf[ks], a1, 0, 0, 0);
    }
    __builtin_amdgcn_s_setprio(0);
  };
  auto sink = [&](int t, const f32x4& a0, const f32x4& a1) {
    const int byb = (t << 4) + (colw >> 3);
    const int bit = colw & 7;
#pragma unroll
    for (int rt = 0; rt < 2; ++rt)
#pragma unroll
      for (int r = 0; r < 4; ++r) {
        const int row = rt * 16 + rowb + r;
        const int live = (bm[row * BMSR + byb] >> bit) & 1;
        const float e = exp2f(rt ? a1[r] : a0[r]);
        ls[rt * 4 + r] += live ? e : 0.0f;
      }
  };

  s16x8 kA[4], kB[4];
#pragma unroll
  for (int ks = 0; ks < 4; ++ks) kA[ks] = *(const s16x8*)(kfp + ks * 32);
#pragma unroll 1
  for (int tp = 0; tp < 4; ++tp) {
    const int t0 = tp << 1;
#pragma unroll
    for (int ks = 0; ks < 4; ++ks)
      kB[ks] = *(const s16x8*)(kfp + (size_t)(t0 + 1) * (128 * DD) + ks * 32);
    f32x4 a0 = {0.f,0.f,0.f,0.f}, a1 = {0.f,0.f,0.f,0.f};
    qk8(kA, a0, a1);
    sink(t0, a0, a1);
#pragma unroll
    for (int ks = 0; ks < 4; ++ks)
      kA[ks] = *(const s16x8*)(kfp + (size_t)((t0 + 2) & 7) * (128 * DD) + ks * 32);
    f32x4 c0 = {0.f,0.f,0.f,0.f}, c1 = {0.f,0.f,0.f,0.f};
    qk8(kB, c0, c1);
    sink(t0 + 1, c0, c1);
  }

#pragma unroll
  for (int i = 0; i < 8; ++i) {
    float l = ls[i];
#pragma unroll
    for (int d = 1; d < 16; d <<= 1) l += __shfl_xor(l, d);
    ls[i] = l;
  }
  if (lrow == 0) {
#pragma unroll
    for (int i = 0; i < 8; ++i)
      redl[w][((i >> 2) << 4) + rowb + (i & 3)] = ls[i];
  }
  __syncthreads();
  if (tid < 32) {
    float l = 0.f;
#pragma unroll
    for (int ww = 0; ww < 8; ++ww) l += redl[ww][tid];
    lpart[(size_t)h * (BB * SQ) + (size_t)b * SQ + q0 + tid] = l;  // block-owned slot
  }
}

// Kernel B: recompute QK on the half, p=exp2*il -> attn (coalesced) + PV partial
// -> out via fp32 atomicAdd (exactly 2 contributors -> deterministic).
__global__ __launch_bounds__(512, 8) void attn_emit(
    const float* __restrict__ q, const unsigned long long* __restrict__ mb,
    const unsigned short* __restrict__ kb, const unsigned short* __restrict__ vt,
    const float* __restrict__ lpart, float* __restrict__ outp,
    float* __restrict__ attn) {
  __shared__ unsigned char bm[32 * BMSR];
  __shared__ __align__(16) unsigned short p_lds[2][32][LDP];
  __shared__ float il_s[32];
  const int tid = threadIdx.x;
  const int bid = blockIdx.x;
  const int swz = ((bid & 7) << 7) + (bid >> 3);
  const int b  = swz >> 7;
  const int h  = swz & 1;
  const int q0 = ((swz >> 1) & 63) << 5;
  const int k0 = h << 10;
  const int lane = tid & 63, w = tid >> 6, lrow = lane & 15, lk = lane >> 4;
  const int rowb = lk << 2;
  const int colw = (w << 4) + lrow;

  {
    const int row = tid >> 4, wd = tid & 15;
    *(unsigned long long*)&bm[row * BMSR + (wd << 3)] =
        mb[(size_t)(b * SQ + q0 + row) * 32 + h * 16 + wd];
  }
  if (tid < 32) {
    const size_t idx = (size_t)b * SQ + q0 + tid;
    il_s[tid] = 1.0f / (lpart[idx] + lpart[idx + (size_t)BB * SQ]);
  }

  s16x8 af0[4], af1[4];
#pragma unroll
  for (int ks = 0; ks < 4; ++ks) {
    const float* qp0 = q + ((size_t)(b * SQ + q0 + lrow)) * DD + ks * 32 + lk * 8;
    const float* qp1 = qp0 + 16 * DD;
    const float4 a0 = *(const float4*)qp0;
    const float4 a1 = *(const float4*)(qp0 + 4);
    const float4 c0 = *(const float4*)qp1;
    const float4 c1 = *(const float4*)(qp1 + 4);
    s16x8 x, y;
    x[0] = (short)f2bf(a0.x); x[1] = (short)f2bf(a0.y); x[2] = (short)f2bf(a0.z); x[3] = (short)f2bf(a0.w);
    x[4] = (short)f2bf(a1.x); x[5] = (short)f2bf(a1.y); x[6] = (short)f2bf(a1.z); x[7] = (short)f2bf(a1.w);
    y[0] = (short)f2bf(c0.x); y[1] = (short)f2bf(c0.y); y[2] = (short)f2bf(c0.z); y[3] = (short)f2bf(c0.w);
    y[4] = (short)f2bf(c1.x); y[5] = (short)f2bf(c1.y); y[6] = (short)f2bf(c1.z); y[7] = (short)f2bf(c1.w);
    af0[ks] = x; af1[ks] = y;
  }

  const unsigned short* kfp = kb + ((size_t)(b * SK + k0 + colw)) * DD + lk * 8;
  __syncthreads();  // bm + il_s ready

  float il[8];
#pragma unroll
  for (int i = 0; i < 8; ++i)
    il[i] = il_s[((i >> 2) << 4) + rowb + (i & 3)];

  f32x4 o0 = {0.f,0.f,0.f,0.f}, o1 = {0.f,0.f,0.f,0.f};
  const unsigned short* vbase = vt + ((size_t)(b * DD + colw)) * SK + k0 + lk * 8;
  const int arow = tid >> 4;          // 0..31
  const int acol0 = (tid & 15) << 3;  // 0..120
  float* abase = attn + ((size_t)(b * SQ + q0 + arow)) * SK + k0 + acol0;

#pragma unroll 2
  for (int t = 0; t < 8; ++t) {
    const int buf = t & 1;
    s16x8 kf[4];
#pragma unroll
    for (int ks = 0; ks < 4; ++ks)
      kf[ks] = *(const s16x8*)(kfp + (size_t)t * (128 * DD) + ks * 32);
    f32x4 a0 = {0.f,0.f,0.f,0.f}, a1 = {0.f,0.f,0.f,0.f};
    __builtin_amdgcn_s_setprio(1);
#pragma unroll
    for (int ks = 0; ks < 4; ++ks) {
      a0 = __builtin_amdgcn_mfma_f32_16x16x32_bf16(af0[ks], kf[ks], a0, 0, 0, 0);
      a1 = __builtin_amdgcn_mfma_f32_16x16x32_bf16(af1[ks], kf[ks], a1, 0, 0, 0);
    }
    __builtin_amdgcn_s_setprio(0);
    const int byb = (t << 4) + (colw >> 3);
    const int bit = colw & 7;
#pragma unroll
    for (int rt = 0; rt < 2; ++rt)
#pragma unroll
      for (int r = 0; r < 4; ++r) {
        const int row = rt * 16 + rowb + r;
        const int live = (bm[row * BMSR + byb] >> bit) & 1;
        const float e = exp2f(rt ? a1[r] : a0[r]) * il[rt * 4 + r];
        p_lds[buf][row][colw] = f2bf(live ? e : 0.0f);
      }
    bar_lds();  // publish p tile
    {  // attn store: 16 lanes x 32B = 512B contiguous per row-run
      const s16x8 pr = *(const s16x8*)(&p_lds[buf][arow][acol0]);
      float4 g0, g1;
      g0.x = bf2f((unsigned short)pr[0]); g0.y = bf2f((unsigned short)pr[1]);
      g0.z = bf2f((unsigned short)pr[2]); g0.w = bf2f((unsigned short)pr[3]);
      g1.x = bf2f((unsigned short)pr[4]); g1.y = bf2f((unsigned short)pr[5]);
      g1.z = bf2f((unsigned short)pr[6]); g1.w = bf2f((unsigned short)pr[7]);
      float* ap = abase + (t << 7);
      *(float4*)ap = g0;
      *(float4*)(ap + 4) = g1;
    }
    // PV partial over this chunk
    __builtin_amdgcn_s_setprio(1);
#pragma unroll
    for (int ks = 0; ks < 4; ++ks) {
      const s16x8 pa0 = *(const s16x8*)(&p_lds[buf][lrow][ks * 32 + lk * 8]);
      const s16x8 pa1 = *(const s16x8*)(&p_lds[buf][16 + lrow][ks * 32 + lk * 8]);
      const s16x8 vf = *(const s16x8*)(vbase + (t << 7) + ks * 32);
      o0 = __builtin_amdgcn_mfma_f32_16x16x32_bf16(pa0, vf, o0, 0, 0, 0);
      o1 = __builtin_amdgcn_mfma_f32_16x16x32_bf16(pa1, vf, o1, 0, 0, 0);
    }
    __builtin_amdgcn_s_setprio(0);
  }

  // out += PV partial (2 contributors/element total -> exact, deterministic)
#pragma unroll
  for (int rt = 0; rt < 2; ++rt)
#pragma unroll
    for (int r = 0; r < 4; ++r) {
      const int row = q0 + rt * 16 + rowb + r;
      atomicAdd(outp + ((size_t)(b * SQ + row)) * DD + colw, rt ? o1[r] : o0[r]);
    }
}

extern "C" void kernel_launch(void* const* d_in, const int* in_sizes, int n_in,
                              void* d_out, int out_size, void* d_ws, size_t ws_size,
                              hipStream_t stream) {
  const float* q = (const float*)d_in[0];
  const float* k = (const float*)d_in[1];
  const float* v = (const float*)d_in[2];
  const int* mask = (const int*)d_in[3];
  float* outp = (float*)d_out;
  float* attn = outp + (size_t)BB * SQ * DD;

  unsigned short* kb = (unsigned short*)d_ws;                       // 4 MB
  unsigned short* vt = kb + (size_t)BB * SK * DD;                   // 4 MB
  unsigned long long* mbits = (unsigned long long*)(vt + (size_t)BB * SK * DD);  // 4 MB
  float* lpart = (float*)(mbits + (size_t)BB * SQ * (SK / 64));     // 128 KB

  hipMemsetAsync(outp, 0, (size_t)BB * SQ * DD * sizeof(float), stream);  // out: atomic target
  prep_all<<<1024 + 256 + 4096, 256, 0, stream>>>(k, v, mask, kb, vt, mbits);
  attn_lsum<<<1024, 512, 0, stream>>>(q, mbits, kb, lpart);
  attn_emit<<<1024, 512, 0, stream>>>(q, mbits, kb, vt, lpart, outp, attn);
}

// Round 12
// 239.405 us; speedup vs baseline: 1.6030x; 1.6030x over previous
//
#include <hip/hip_runtime.h>
#include <hip/hip_bf16.h>

#define BB 8
#define SQ 2048
#define SK 2048
#define DD 128
// 1/sqrt(128) * log2(e): K pre-scaled so QK acc feeds exp2 directly
#define KSCALE 0.12751649736401815f

using s16x8 = __attribute__((ext_vector_type(8))) short;
using s16x4 = __attribute__((ext_vector_type(4))) short;
using f32x4 = __attribute__((ext_vector_type(4))) float;

__device__ __forceinline__ unsigned short f2bf(float f) {
  union { float f; unsigned u; } v; v.f = f;
  unsigned r = v.u + 0x7FFFu + ((v.u >> 16) & 1u);
  return (unsigned short)(r >> 16);
}
__device__ __forceinline__ float bf2f(unsigned short h) {
  union { unsigned u; float f; } v; v.u = ((unsigned)h) << 16; return v.f;
}

// Merged prep: [0,1024) K->bf16*KSCALE; [1024,1280) V->bf16 V^T
__global__ __launch_bounds__(256) void prep_all(
    const float* __restrict__ k, const float* __restrict__ v,
    unsigned short* __restrict__ kb, unsigned short* __restrict__ vt) {
  const int bid = blockIdx.x;
  const int tid = threadIdx.x;
  if (bid < 1024) {            // ---- K scale+convert ----
    const size_t i = ((size_t)bid * 256 + tid) * 8;
    const float4 a = *(const float4*)(k + i);
    const float4 c = *(const float4*)(k + i + 4);
    ushort4 o0, o1;
    o0.x = f2bf(a.x * KSCALE); o0.y = f2bf(a.y * KSCALE);
    o0.z = f2bf(a.z * KSCALE); o0.w = f2bf(a.w * KSCALE);
    o1.x = f2bf(c.x * KSCALE); o1.y = f2bf(c.y * KSCALE);
    o1.z = f2bf(c.z * KSCALE); o1.w = f2bf(c.w * KSCALE);
    *(ushort4*)(kb + i) = o0;
    *(ushort4*)(kb + i + 4) = o1;
  } else {                     // ---- V transpose ----
    constexpr int TS = 132;
    __shared__ __align__(16) unsigned short tile[64 * TS];
    const int vb = bid - 1024;
    const int b  = vb >> 5;
    const int k0 = (vb & 31) << 6;
#pragma unroll
    for (int p = 0; p < 8; ++p) {
      const int row = p * 8 + (tid >> 5);
      const int c4  = (tid & 31) << 2;
      const float4 vv = *(const float4*)(v + ((size_t)(b * SK + k0 + row)) * DD + c4);
      ushort4 o; o.x = f2bf(vv.x); o.y = f2bf(vv.y); o.z = f2bf(vv.z); o.w = f2bf(vv.w);
      *(ushort4*)(&tile[row * TS + c4]) = o;
    }
    __syncthreads();
#pragma unroll
    for (int p = 0; p < 8; ++p) {
      const int u = p * 256 + tid;
      const int d  = u >> 4;
      const int kw = (u & 15) << 2;
      ushort4 o;
      o.x = tile[(kw + 0) * TS + d];
      o.y = tile[(kw + 1) * TS + d];
      o.z = tile[(kw + 2) * TS + d];
      o.w = tile[(kw + 3) * TS + d];
      *(ushort4*)(vt + ((size_t)(b * DD + d)) * SK + k0 + kw) = o;
    }
  }
}

// Single-pass fused attention, 16 q-rows/block, P(=e, unnormalized bf16) in a
// 64KB LDS buffer. 8 waves, each owning a private 256-k slice: the entire main
// loop (QK -> exp2 -> P-store -> PV accumulate) is barrier-free (intra-wave
// lgkmcnt only). One QK pass, one exp pass (half the work of the 2-pass champ).
// Epilogue: block-reduce l, out = (merged O)*il, attn = P*il streamed coalesced.
#define PSTR 2056   // P row stride (ushorts)
#define BMSR 264    // mask-bit row stride (bytes)
#define OBS  132    // obuf row stride (floats)

__global__ __launch_bounds__(512, 4) void fused_attn(
    const float* __restrict__ q, const int* __restrict__ mask,
    const unsigned short* __restrict__ kb, const unsigned short* __restrict__ vt,
    float* __restrict__ outp, float* __restrict__ attn) {
  __shared__ __align__(16) unsigned short P[16 * PSTR];  // 65,792 B
  __shared__ unsigned char bm[16 * BMSR];                //  4,224 B
  __shared__ float obuf[16 * OBS];                       //  8,448 B
  __shared__ float redl[8][16];                          //    512 B
  __shared__ float il_s[16];                             //     64 B

  const int tid = threadIdx.x;
  const int bid = blockIdx.x;
  // 1024 blocks = 8 XCD x 128 (bijective): batch pinned to one XCD, kb/vt L2-hot
  const int swz = ((bid & 7) << 7) + (bid >> 3);
  const int b  = swz >> 7;
  const int q0 = (swz & 127) << 4;   // 16 q-rows
  const int lane = tid & 63;
  const int w    = tid >> 6;         // wave 0..7
  const int lrow = lane & 15;
  const int lk   = lane >> 4;
  const int rowb = lk << 2;
  const int slice0 = w << 8;         // wave's private 256-k slice

  // zero O accumulator
#pragma unroll
  for (int i = 0; i < 4; ++i) obuf[tid + (i << 9)] = 0.0f;
  if (tid < 16 * OBS - 2048) obuf[2048 + tid] = 0.0f;

  // mask ingest: 16 rows x 2048 -> 1 bit/elem (8/byte); 8 x (2 int4) per thread
  {
    const int* mbase = mask + ((size_t)(b * SQ + q0)) * SK;
#pragma unroll
    for (int i = 0; i < 8; ++i) {
      const int u = (i << 9) + tid;
      const int grow = u >> 8;      // row 0..15
      const int gb   = u & 255;     // byte (8-col group)
      const int* pp = mbase + (size_t)grow * SK + ((size_t)gb << 3);
      const int4 m0 = *(const int4*)pp;
      const int4 m1 = *(const int4*)(pp + 4);
      unsigned bv = (unsigned)(m0.x != 0) | ((unsigned)(m0.y != 0) << 1) |
                    ((unsigned)(m0.z != 0) << 2) | ((unsigned)(m0.w != 0) << 3) |
                    ((unsigned)(m1.x != 0) << 4) | ((unsigned)(m1.y != 0) << 5) |
                    ((unsigned)(m1.z != 0) << 6) | ((unsigned)(m1.w != 0) << 7);
      bm[grow * BMSR + gb] = (unsigned char)bv;
    }
  }

  // Q A-fragments (16 rows x 128 d)
  s16x8 af[4];
#pragma unroll
  for (int ks = 0; ks < 4; ++ks) {
    const float* qp = q + ((size_t)(b * SQ + q0 + lrow)) * DD + ks * 32 + lk * 8;
    const float4 a0 = *(const float4*)qp;
    const float4 a1 = *(const float4*)(qp + 4);
    s16x8 x;
    x[0] = (short)f2bf(a0.x); x[1] = (short)f2bf(a0.y); x[2] = (short)f2bf(a0.z); x[3] = (short)f2bf(a0.w);
    x[4] = (short)f2bf(a1.x); x[5] = (short)f2bf(a1.y); x[6] = (short)f2bf(a1.z); x[7] = (short)f2bf(a1.w);
    af[ks] = x;
  }

  const unsigned short* kfp = kb + ((size_t)(b * SK + slice0 + lrow)) * DD + lk * 8;
  const unsigned short* vfp = vt + ((size_t)(b * DD + lrow)) * SK + slice0 + lk * 8;

  __syncthreads();  // bm + obuf ready

  float ls[4] = {0.f, 0.f, 0.f, 0.f};
  f32x4 o[8];
#pragma unroll
  for (int nt = 0; nt < 8; ++nt) o[nt] = f32x4{0.f, 0.f, 0.f, 0.f};

  // ---- main loop: 8 chunks of 32 k. Barrier-free (wave-private slice). ----
#pragma unroll 1
  for (int c = 0; c < 8; ++c) {
    // K frags for both 16-col tiles of this chunk
    s16x8 kf[8];
#pragma unroll
    for (int t2 = 0; t2 < 2; ++t2)
#pragma unroll
      for (int ks = 0; ks < 4; ++ks)
        kf[t2 * 4 + ks] = *(const s16x8*)(kfp + (size_t)(((c << 1) + t2) << 4) * DD + ks * 32);
    // first half of V frags (d 0..63)
    s16x8 vf[4];
#pragma unroll
    for (int nt = 0; nt < 4; ++nt)
      vf[nt] = *(const s16x8*)(vfp + (size_t)(nt << 4) * SK + (c << 5));

    // QK + exp2 + P-store for the 2 tiles
#pragma unroll
    for (int t2 = 0; t2 < 2; ++t2) {
      f32x4 acc = {0.f, 0.f, 0.f, 0.f};
      __builtin_amdgcn_s_setprio(1);
#pragma unroll
      for (int ks = 0; ks < 4; ++ks)
        acc = __builtin_amdgcn_mfma_f32_16x16x32_bf16(af[ks], kf[t2 * 4 + ks], acc, 0, 0, 0);
      __builtin_amdgcn_s_setprio(0);
      const int colg = slice0 + (c << 5) + (t2 << 4) + lrow;
      const int byb = colg >> 3, bit = colg & 7;
#pragma unroll
      for (int r = 0; r < 4; ++r) {
        const int row = rowb + r;
        const int live = (bm[row * BMSR + byb] >> bit) & 1;
        float e = exp2f(acc[r]);
        e = live ? e : 0.0f;
        ls[r] += e;
        P[row * PSTR + colg] = f2bf(e);
      }
    }
    // second half of V frags (d 64..127)
    s16x8 vg[4];
#pragma unroll
    for (int nt = 0; nt < 4; ++nt)
      vg[nt] = *(const s16x8*)(vfp + (size_t)((nt + 4) << 4) * SK + (c << 5));

    // own P writes -> own A-frag read: intra-wave only
    asm volatile("s_waitcnt lgkmcnt(0)" ::: "memory");
    __builtin_amdgcn_sched_barrier(0);
    const s16x8 pa = *(const s16x8*)(&P[lrow * PSTR + slice0 + (c << 5) + (lk << 3)]);
    __builtin_amdgcn_s_setprio(1);
#pragma unroll
    for (int nt = 0; nt < 4; ++nt)
      o[nt] = __builtin_amdgcn_mfma_f32_16x16x32_bf16(pa, vf[nt], o[nt], 0, 0, 0);
#pragma unroll
    for (int nt = 0; nt < 4; ++nt)
      o[nt + 4] = __builtin_amdgcn_mfma_f32_16x16x32_bf16(pa, vg[nt], o[nt + 4], 0, 0, 0);
    __builtin_amdgcn_s_setprio(0);
  }

  // ---- l reduce: shfl over 16-lane col group -> cross-wave via LDS ----
#pragma unroll
  for (int r = 0; r < 4; ++r) {
    float l = ls[r];
#pragma unroll
    for (int d = 1; d < 16; d <<= 1) l += __shfl_xor(l, d);
    ls[r] = l;
  }
  if (lrow == 0) {
#pragma unroll
    for (int r = 0; r < 4; ++r) redl[w][rowb + r] = ls[r];
  }
  __syncthreads();  // all P complete + redl complete
  if (tid < 16) {
    float l = 0.f;
#pragma unroll
    for (int ww = 0; ww < 8; ++ww) l += redl[ww][tid];
    il_s[tid] = 1.0f / l;
  }
  // merge wave O partials (distinct k-slices -> 8 contributors per element)
#pragma unroll
  for (int nt = 0; nt < 8; ++nt)
#pragma unroll
    for (int r = 0; r < 4; ++r)
      atomicAdd(&obuf[(rowb + r) * OBS + (nt << 4) + lrow], o[nt][r]);
  __syncthreads();  // il_s + obuf complete

  // ---- out = O * il (coalesced) ----
  {
    const int orow = tid >> 5;          // 0..15
    const int ocg  = (tid & 31) << 2;   // 0..124
    const float ilr = il_s[orow];
    const float* ob = &obuf[orow * OBS + ocg];
    float4 u;
    u.x = ob[0] * ilr; u.y = ob[1] * ilr; u.z = ob[2] * ilr; u.w = ob[3] * ilr;
    *(float4*)(outp + ((size_t)(b * SQ + q0 + orow)) * DD + ocg) = u;
  }

  // ---- attn = P * il, streamed coalesced (512B runs) ----
  {
    const int arow = tid >> 5;          // 0..15
    const int acg  = (tid & 31) << 2;   // 4 cols per thread per step
    const float ilr = il_s[arow];
    const unsigned short* prow = &P[arow * PSTR];
    float* abase = attn + ((size_t)(b * SQ + q0 + arow)) * SK;
#pragma unroll 4
    for (int i = 0; i < 16; ++i) {
      const int c0 = (i << 7) + acg;
      const s16x4 pr = *(const s16x4*)(&prow[c0]);
      float4 g;
      g.x = bf2f((unsigned short)pr[0]) * ilr;
      g.y = bf2f((unsigned short)pr[1]) * ilr;
      g.z = bf2f((unsigned short)pr[2]) * ilr;
      g.w = bf2f((unsigned short)pr[3]) * ilr;
      *(float4*)(abase + c0) = g;
    }
  }
}

extern "C" void kernel_launch(void* const* d_in, const int* in_sizes, int n_in,
                              void* d_out, int out_size, void* d_ws, size_t ws_size,
                              hipStream_t stream) {
  const float* q = (const float*)d_in[0];
  const float* k = (const float*)d_in[1];
  const float* v = (const float*)d_in[2];
  const int* mask = (const int*)d_in[3];
  float* outp = (float*)d_out;
  float* attn = outp + (size_t)BB * SQ * DD;

  unsigned short* kb = (unsigned short*)d_ws;                       // 8 MB
  unsigned short* vt = kb + (size_t)BB * SK * DD;                   // 8 MB

  prep_all<<<1280, 256, 0, stream>>>(k, v, kb, vt);
  fused_attn<<<BB * (SQ / 16), 512, 0, stream>>>(q, mask, kb, vt, outp, attn);
}